// Round 1
// baseline (295.650 us; speedup 1.0000x reference)
//
#include <hip/hip_runtime.h>
#include <hip/hip_bf16.h>
#include <hip/hip_fp16.h>

// 3-layer GCN + FC head. No-prescan padded two-pass radix preprocessing:
//   k_init  : cursors = fixed region starts (super s: s*capS; bucket b: b*capB)
//   k_bin1  : bin edges by dst-super (25 regions), LDS rank, clustered writes
//   k_bin2  : bin by dst-bucket within super (782 padded regions)
//   k_sortb2: per-bucket counting sort -> padded ssort + row2[n]={beg,end} + dinv
// Layers:
//   k_prep1 : p4 = dinv*x
//   k_l1g   : agg3 -> relu(.@W11+b11) -> @W12*dinv -> g (fp16, 2 channel planes)
//   k_agg8p : gather one 16-ch plane of g -> h half-row = relu(dinv*acc+b12)
//             (2 dispatches; each plane = 3.2 MB -> L2-resident per XCD)
//   k_gemv32h: g = fp16((h@W13)*dinv)  (plane layout)
//   k_aggfc8: gather one plane -> relu(dinv*acc+b13).fcw partial; pass1 adds fcb

#define RBITS  7
#define RNODES 128
#define SBITS  12
#define SNODES 4096
#define BPS    32
#define SMAX   32
#define CE     4096
#define EPT    16

// ---------- preprocessing ----------
__global__ void k_init(int S, int B, int capS, int capB,
                       int* __restrict__ gcur1, int* __restrict__ gcur2) {
    int t = blockIdx.x * blockDim.x + threadIdx.x;
    if (t < S) gcur1[t] = t * capS;
    if (t < B) gcur2[t] = t * capB;
}

__global__ void k_bin1(const int* __restrict__ src, const int* __restrict__ dst, int E, int S,
                       int* __restrict__ gcur1, unsigned* __restrict__ binned1) {
    __shared__ int cnt[SMAX * 8];
    __shared__ int repOff[SMAX * 8];
    __shared__ int runS[SMAX];
    int tid = threadIdx.x, rep = tid & 7;
    for (int i = tid; i < SMAX * 8; i += 256) cnt[i] = 0;
    __syncthreads();
    int e0 = blockIdx.x * CE;
    int pk[EPT], rnk[EPT], sup[EPT];
#pragma unroll
    for (int j = 0; j < EPT; j++) {
        int e = e0 + j * 256 + tid;
        if (e < E) {
            int d = __builtin_nontemporal_load(dst + e);
            sup[j] = d >> SBITS;
            pk[j]  = (__builtin_nontemporal_load(src + e) << SBITS) | (d & (SNODES - 1));
            rnk[j] = atomicAdd(&cnt[sup[j] * 8 + rep], 1);
        } else sup[j] = -1;
    }
    __syncthreads();
    if (tid < S) {
        int tot = 0;
#pragma unroll
        for (int r = 0; r < 8; r++) { repOff[tid * 8 + r] = tot; tot += cnt[tid * 8 + r]; }
        runS[tid] = tot ? atomicAdd(&gcur1[tid], tot) : 0;
    }
    __syncthreads();
#pragma unroll
    for (int j = 0; j < EPT; j++)
        if (sup[j] >= 0)
            binned1[runS[sup[j]] + repOff[sup[j] * 8 + rep] + rnk[j]] = (unsigned)pk[j];
}

__global__ void k_bin2(const unsigned* __restrict__ binned1, const int* __restrict__ fillEnd,
                       int S, int capS, int* __restrict__ gcur2, unsigned* __restrict__ binned2) {
    __shared__ int send[SMAX];
    __shared__ int cnt[64 * 4];
    __shared__ int repOff[64 * 4];
    __shared__ int runS[64];
    int tid = threadIdx.x, rep = tid & 3;
    if (tid < S) send[tid] = fillEnd[tid];
    for (int i = tid; i < 64 * 4; i += 256) cnt[i] = 0;
    __syncthreads();
    int i0 = blockIdx.x * CE;
    int s0 = i0 / capS;
    int Sc = S * capS;
    unsigned pk[EPT];
    int rnk[EPT], rb[EPT];
#pragma unroll
    for (int j = 0; j < EPT; j++) {
        int idx = i0 + j * 256 + tid;
        rb[j] = -1;
        if (idx < Sc) {
            int sp = idx / capS;
            if (idx < send[sp]) {
                unsigned p = __builtin_nontemporal_load(binned1 + idx);
                int relB = ((sp - s0) << 5) | ((p >> RBITS) & (BPS - 1));
                pk[j] = p; rb[j] = relB;
                rnk[j] = atomicAdd(&cnt[relB * 4 + rep], 1);
            }
        }
    }
    __syncthreads();
    if (tid < 64) {
        int tot = 0;
#pragma unroll
        for (int r = 0; r < 4; r++) { repOff[tid * 4 + r] = tot; tot += cnt[tid * 4 + r]; }
        int sp = s0 + (tid >> 5);
        if (tot && sp < S) {
            int gb = sp * BPS + (tid & (BPS - 1));
            runS[tid] = atomicAdd(&gcur2[gb], tot);
        }
    }
    __syncthreads();
#pragma unroll
    for (int j = 0; j < EPT; j++)
        if (rb[j] >= 0) {
            unsigned p = pk[j];
            binned2[runS[rb[j]] + repOff[rb[j] * 4 + rep] + rnk[j]] =
                ((p >> SBITS) << RBITS) | (p & (RNODES - 1));
        }
}

// per-bucket counting sort -> padded ssort, row2[n]={beg,end}, dinv
__global__ void k_sortb2(const unsigned* __restrict__ binned2, const int* __restrict__ gcur2,
                         int capB, int N, int* __restrict__ ssort,
                         int2* __restrict__ row2, float* __restrict__ dinv) {
    __shared__ int cnt[RNODES];
    __shared__ int loc[RNODES];
    int b = blockIdx.x, tid = threadIdx.x;
    int beg = b * capB, end = gcur2[b];
    if (tid < RNODES) cnt[tid] = 0;
    __syncthreads();
    for (int idx = beg + tid; idx < end; idx += 256)
        atomicAdd(&cnt[__builtin_nontemporal_load(binned2 + idx) & (RNODES - 1)], 1);
    __syncthreads();
    if (tid < RNODES) loc[tid] = cnt[tid];
    __syncthreads();
    for (int off = 1; off < RNODES; off <<= 1) {
        int v = 0;
        if (tid < RNODES && tid >= off) v = loc[tid - off];
        __syncthreads();
        if (tid < RNODES) loc[tid] += v;
        __syncthreads();
    }
    int n0 = b << RBITS;
    if (tid < RNODES) {
        int excl = loc[tid] - cnt[tid];
        loc[tid] = beg + excl;
        int n = n0 + tid;
        if (n < N) {
            row2[n] = make_int2(beg + excl, beg + excl + cnt[tid]);
            dinv[n] = rsqrtf((float)cnt[tid] + 1.0f);   // +1 self loop
        }
    }
    if (tid < RNODES) cnt[tid] = 0;               // reuse as cursor
    __syncthreads();
    for (int idx = beg + tid; idx < end; idx += 256) {
        unsigned p = __builtin_nontemporal_load(binned2 + idx);
        int dl = (int)(p & (RNODES - 1));
        int r  = atomicAdd(&cnt[dl], 1);
        ssort[loc[dl] + r] = (int)(p >> RBITS);
    }
}

// ---------- layer 1 (+W12 fused) ----------
__global__ void k_prep1(const float* __restrict__ x, const float* __restrict__ dinv,
                        float4* __restrict__ p4, int N) {
    int n = blockIdx.x * blockDim.x + threadIdx.x;
    if (n >= N) return;
    float di = dinv[n];
    p4[n] = make_float4(x[n * 3] * di, x[n * 3 + 1] * di, x[n * 3 + 2] * di, 0.f);
}

// 32 lanes/node: lane-strided gather of p4[src], xor reduce-all, h1 per lane,
// then h1 @ W12 via LDS-staged h1 (broadcast reads, no permutes). No h in memory.
// g written in 2-plane layout: plane (c>>4), idx n*16 + (c&15).
__global__ void k_l1g(const int2* __restrict__ row2, const int* __restrict__ ssort,
                      const float4* __restrict__ p4, const float* __restrict__ dinv,
                      const float* __restrict__ W1, const float* __restrict__ b1,
                      const float* __restrict__ W2, __half* __restrict__ g2, int N) {
    __shared__ float sW1[96];
    __shared__ float sb1[32];
    __shared__ float sW2[1024];
    __shared__ float sh1[256];
    int tid = threadIdx.x;
    for (int i = tid; i < 1024; i += 256) sW2[i] = W2[i];
    if (tid < 96) sW1[tid] = W1[tid];
    if (tid < 32) sb1[tid] = b1[tid];
    __syncthreads();
    int t = blockIdx.x * 256 + tid;
    int n = t >> 5, c = t & 31;
    bool active = (n < N);
    float ax = 0.f, ay = 0.f, az = 0.f;
    float di = 0.f;
    if (active) {
        int2 r = row2[n];
        for (int idx = r.x + c; idx < r.y; idx += 32) {
            float4 q = p4[__builtin_nontemporal_load(ssort + idx)];
            ax += q.x; ay += q.y; az += q.z;
        }
    }
#pragma unroll
    for (int off = 16; off; off >>= 1) {
        ax += __shfl_xor(ax, off, 32);
        ay += __shfl_xor(ay, off, 32);
        az += __shfl_xor(az, off, 32);
    }
    float h1 = 0.f;
    if (active) {
        float4 me = p4[n];
        di = dinv[n];
        ax = di * (ax + me.x); ay = di * (ay + me.y); az = di * (az + me.z);
        h1 = fmaxf(ax * sW1[c] + ay * sW1[32 + c] + az * sW1[64 + c] + sb1[c], 0.f);
    }
    sh1[tid] = h1;
    __syncthreads();
    if (!active) return;
    const float* hr = sh1 + (tid >> 5) * 32;
    float acc = 0.f;
#pragma unroll
    for (int k = 0; k < 32; k++) acc += hr[k] * sW2[k * 32 + c];
    size_t NP = (size_t)N * 16;
    g2[(size_t)(c >> 4) * NP + (size_t)n * 16 + (c & 15)] = __float2half_rn(acc * di);
}

// ---------- aggregate one 16-channel plane: 8 lanes/node, lane = 2 channels ----
// gp points at one plane ([N][8] half2 = 3.2 MB -> fits per-XCD L2).
// hp points at h + plane*16; bias pre-offset by plane*16.
__global__ void k_agg8p(const int2* __restrict__ row2, const int* __restrict__ ssort,
                        const __half2* __restrict__ gp, const float* __restrict__ dinv,
                        const float* __restrict__ bias, float* __restrict__ hp, int N) {
    int t = blockIdx.x * blockDim.x + threadIdx.x;
    int n = t >> 3, l = t & 7;
    if (n >= N) return;
    int2 r = row2[n];
    int beg = r.x, end = r.y;
    float ax = 0.f, ay = 0.f, bx = 0.f, by = 0.f;
    float cx = 0.f, cy = 0.f, dx = 0.f, dy = 0.f;
    for (int base = beg; base < end; base += 8) {
        int m = end - base; if (m > 8) m = 8;
        int myS = (l < m) ? __builtin_nontemporal_load(ssort + base + l) : 0;
        int i = 0;
        for (; i + 4 <= m; i += 4) {
            int s0 = __shfl(myS, i,     8);
            int s1 = __shfl(myS, i + 1, 8);
            int s2 = __shfl(myS, i + 2, 8);
            int s3 = __shfl(myS, i + 3, 8);
            float2 q0 = __half22float2(gp[(size_t)s0 * 8 + l]);
            float2 q1 = __half22float2(gp[(size_t)s1 * 8 + l]);
            float2 q2 = __half22float2(gp[(size_t)s2 * 8 + l]);
            float2 q3 = __half22float2(gp[(size_t)s3 * 8 + l]);
            ax += q0.x; ay += q0.y;
            bx += q1.x; by += q1.y;
            cx += q2.x; cy += q2.y;
            dx += q3.x; dy += q3.y;
        }
        for (; i < m; i++) {
            int s = __shfl(myS, i, 8);
            float2 q = __half22float2(gp[(size_t)s * 8 + l]);
            ax += q.x; ay += q.y;
        }
    }
    float2 self = __half22float2(gp[(size_t)n * 8 + l]);
    float sx = ((ax + bx) + (cx + dx)) + self.x;
    float sy = ((ay + by) + (cy + dy)) + self.y;
    float di = dinv[n];
    int c0 = l * 2;
    float2 o = make_float2(fmaxf(di * sx + bias[c0], 0.f),
                           fmaxf(di * sy + bias[c0 + 1], 0.f));
    double od; __builtin_memcpy(&od, &o, 8);
    __builtin_nontemporal_store(od, (double*)(hp + (size_t)n * 32 + c0));
}

// ---------- gemv h -> fp16 g (plane layout) ----------
__global__ void k_gemv32h(const float* __restrict__ h, const float* __restrict__ W,
                          const float* __restrict__ dinv, __half* __restrict__ g, int N) {
    __shared__ float sW[1024];
    __shared__ float sh[256];
    int tid = threadIdx.x;
    for (int i = tid; i < 1024; i += 256) sW[i] = W[i];
    int t = blockIdx.x * 256 + tid;
    if (t < N * 32) sh[tid] = h[t];
    __syncthreads();
    int n = t >> 5, c = t & 31;
    if (n >= N) return;
    const float* hr = sh + (tid >> 5) * 32;
    float acc = 0.f;
#pragma unroll
    for (int k = 0; k < 32; k++) acc += hr[k] * sW[k * 32 + c];
    size_t NP = (size_t)N * 16;
    g[(size_t)(c >> 4) * NP + (size_t)n * 16 + (c & 15)] = __float2half_rn(acc * dinv[n]);
}

// ---------- layer 3 aggregate plane + FC head (2 passes) ----------
__global__ void k_aggfc8(const int2* __restrict__ row2, const int* __restrict__ ssort,
                         const __half2* __restrict__ gp, const float* __restrict__ dinv,
                         const float* __restrict__ bias, const float* __restrict__ fcw,
                         const float* __restrict__ fcb, float* __restrict__ partial,
                         float* __restrict__ out, int N, int pass) {
    int t = blockIdx.x * blockDim.x + threadIdx.x;
    int n = t >> 3, l = t & 7;
    if (n >= N) return;
    int2 r = row2[n];
    int beg = r.x, end = r.y;
    float ax = 0.f, ay = 0.f, bx = 0.f, by = 0.f;
    float cx = 0.f, cy = 0.f, dx = 0.f, dy = 0.f;
    for (int base = beg; base < end; base += 8) {
        int m = end - base; if (m > 8) m = 8;
        int myS = (l < m) ? __builtin_nontemporal_load(ssort + base + l) : 0;
        int i = 0;
        for (; i + 4 <= m; i += 4) {
            int s0 = __shfl(myS, i,     8);
            int s1 = __shfl(myS, i + 1, 8);
            int s2 = __shfl(myS, i + 2, 8);
            int s3 = __shfl(myS, i + 3, 8);
            float2 q0 = __half22float2(gp[(size_t)s0 * 8 + l]);
            float2 q1 = __half22float2(gp[(size_t)s1 * 8 + l]);
            float2 q2 = __half22float2(gp[(size_t)s2 * 8 + l]);
            float2 q3 = __half22float2(gp[(size_t)s3 * 8 + l]);
            ax += q0.x; ay += q0.y;
            bx += q1.x; by += q1.y;
            cx += q2.x; cy += q2.y;
            dx += q3.x; dy += q3.y;
        }
        for (; i < m; i++) {
            int s = __shfl(myS, i, 8);
            float2 q = __half22float2(gp[(size_t)s * 8 + l]);
            ax += q.x; ay += q.y;
        }
    }
    float2 self = __half22float2(gp[(size_t)n * 8 + l]);
    float sx = ((ax + bx) + (cx + dx)) + self.x;
    float sy = ((ay + by) + (cy + dy)) + self.y;
    float di = dinv[n];
    int c0 = l * 2;
    float v = fmaxf(di * sx + bias[c0], 0.f) * fcw[c0]
            + fmaxf(di * sy + bias[c0 + 1], 0.f) * fcw[c0 + 1];
    v += __shfl_down(v, 4, 8);
    v += __shfl_down(v, 2, 8);
    v += __shfl_down(v, 1, 8);
    if (l == 0) {
        if (pass == 0) {
            __builtin_nontemporal_store(v, partial + n);
        } else {
            out[n] = v + __builtin_nontemporal_load(partial + n) + fcb[0];
        }
    }
}

extern "C" void kernel_launch(void* const* d_in, const int* in_sizes, int n_in,
                              void* d_out, int out_size, void* d_ws, size_t ws_size,
                              hipStream_t stream) {
    const float* x1  = (const float*)d_in[0];
    const int*   ei  = (const int*)d_in[1];
    const float* W11 = (const float*)d_in[2];
    const float* b11 = (const float*)d_in[3];
    const float* W12 = (const float*)d_in[4];
    const float* b12 = (const float*)d_in[5];
    const float* W13 = (const float*)d_in[6];
    const float* b13 = (const float*)d_in[7];
    const float* fcw = (const float*)d_in[8];
    const float* fcb = (const float*)d_in[9];
    float* out = (float*)d_out;

    const int N = in_sizes[0] / 3;
    const int E = in_sizes[1] / 2;
    const int* src = ei;
    const int* dst = ei + E;

    const int B = (N + RNODES - 1) / RNODES;      // 782 buckets
    const int S = (N + SNODES - 1) / SNODES;      // 25 supers
    const int capS = E / S + E / S / 16 + 1024;   // ~7% + 1K slack
    const int capB = E / B + E / B / 4 + 256;     // ~31% slack
    const size_t NC = (size_t)N * 32;

    // workspace layout (4-byte words); keep 8B alignment for h/row2/p4.
    float4*   p4      = (float4*)d_ws;                       // 4N words
    __half*   g       = (__half*)(p4 + N);                   // NC halfs = NC/2 words
    int2*     row2    = (int2*)(g + NC);                     // 2N words
    float*    dinv    = (float*)(row2 + N);                  // N
    int*      gcur1   = (int*)(dinv + N);                    // 32 (padded)
    int*      gcur2   = gcur1 + 32;                          // 800 (padded)
    unsigned* binned1 = (unsigned*)(gcur2 + 800);            // S*capS
    unsigned* binned2 = binned1 + (size_t)S * capS;          // B*capB
    int*      ssort   = (int*)(binned2 + (size_t)B * capB);  // B*capB
    float*    h       = (float*)binned1;                     // NC floats (binned1 dead)
    float*    partial = (float*)binned2;                     // N floats (binned2 dead)

    __half* gA = g;                               // plane 0: channels 0..15
    __half* gB = g + (size_t)N * 16;              // plane 1: channels 16..31

    dim3 blk(256);
    dim3 grid_nc(((int)NC + 255) / 256);
    dim3 grid_n((N + 255) / 256);
    dim3 grid_n8(((N * 8) + 255) / 256);
    dim3 grid_e((E + CE - 1) / CE);
    dim3 grid_sc((S * capS + CE - 1) / CE);
    dim3 grid_b(B);

    // ---- preprocessing (no memsets, no prescan) ----
    k_init<<<dim3((B + 255) / 256), blk, 0, stream>>>(S, B, capS, capB, gcur1, gcur2);
    k_bin1<<<grid_e, blk, 0, stream>>>(src, dst, E, S, gcur1, binned1);
    k_bin2<<<grid_sc, blk, 0, stream>>>(binned1, gcur1, S, capS, gcur2, binned2);
    k_sortb2<<<grid_b, blk, 0, stream>>>(binned2, gcur2, capB, N, ssort, row2, dinv);

    // ---- layer 1 (+ W12 fused) ----
    k_prep1<<<grid_n, blk, 0, stream>>>(x1, dinv, p4, N);
    k_l1g<<<grid_nc, blk, 0, stream>>>(row2, ssort, p4, dinv, W11, b11, W12, g, N);

    // ---- layer 2: two L2-resident plane passes ----
    k_agg8p<<<grid_n8, blk, 0, stream>>>(row2, ssort, (const __half2*)gA, dinv, b12, h, N);
    k_agg8p<<<grid_n8, blk, 0, stream>>>(row2, ssort, (const __half2*)gB, dinv, b12 + 16, h + 16, N);
    k_gemv32h<<<grid_nc, blk, 0, stream>>>(h, W13, dinv, g, N);

    // ---- layer 3 + FC head: two plane passes ----
    k_aggfc8<<<grid_n8, blk, 0, stream>>>(row2, ssort, (const __half2*)gA, dinv, b13, fcw, nullptr, partial, nullptr, N, 0);
    k_aggfc8<<<grid_n8, blk, 0, stream>>>(row2, ssort, (const __half2*)gB, dinv, b13 + 16, fcw + 16, fcb, partial, out, N, 1);
}

// Round 2
// 225.810 us; speedup vs baseline: 1.3093x; 1.3093x over previous
//
#include <hip/hip_runtime.h>
#include <hip/hip_bf16.h>
#include <hip/hip_fp16.h>

// 3-layer GCN + FC head. No-prescan padded two-pass radix preprocessing:
//   k_init  : cursors = fixed region starts (super s: s*capS; bucket b: b*capB)
//   k_bin1  : bin edges by dst-super (25 regions), LDS rank, clustered writes
//   k_bin2  : bin by dst-bucket within super (782 padded regions)
//   k_sortb2: per-bucket counting sort -> padded ssort + row2[n]={beg,end} + dinv
// Layers:
//   k_prep1 : p4 = dinv*x
//   k_l1g   : agg3 -> relu(.@W11+b11) -> @W12*dinv -> g (fp16)  [32 lanes/node]
//   k_agg16 : gather g -> h = relu(dinv*acc+b12)   [16 lanes/node, 8-deep MLP,
//             ssort next-chunk prefetch, nt h store]
//   k_gemv32h: g = fp16((h@W13)*dinv)
//   k_agg16_fc: gather g -> relu(dinv*acc+b13).fcw + fcb -> out [same MLP struct]

#define RBITS  7
#define RNODES 128
#define SBITS  12
#define SNODES 4096
#define BPS    32
#define SMAX   32
#define CE     4096
#define EPT    16

// ---------- preprocessing ----------
__global__ void k_init(int S, int B, int capS, int capB,
                       int* __restrict__ gcur1, int* __restrict__ gcur2) {
    int t = blockIdx.x * blockDim.x + threadIdx.x;
    if (t < S) gcur1[t] = t * capS;
    if (t < B) gcur2[t] = t * capB;
}

__global__ void k_bin1(const int* __restrict__ src, const int* __restrict__ dst, int E, int S,
                       int* __restrict__ gcur1, unsigned* __restrict__ binned1) {
    __shared__ int cnt[SMAX * 8];
    __shared__ int repOff[SMAX * 8];
    __shared__ int runS[SMAX];
    int tid = threadIdx.x, rep = tid & 7;
    for (int i = tid; i < SMAX * 8; i += 256) cnt[i] = 0;
    __syncthreads();
    int e0 = blockIdx.x * CE;
    int pk[EPT], rnk[EPT], sup[EPT];
#pragma unroll
    for (int j = 0; j < EPT; j++) {
        int e = e0 + j * 256 + tid;
        if (e < E) {
            int d = __builtin_nontemporal_load(dst + e);
            sup[j] = d >> SBITS;
            pk[j]  = (__builtin_nontemporal_load(src + e) << SBITS) | (d & (SNODES - 1));
            rnk[j] = atomicAdd(&cnt[sup[j] * 8 + rep], 1);
        } else sup[j] = -1;
    }
    __syncthreads();
    if (tid < S) {
        int tot = 0;
#pragma unroll
        for (int r = 0; r < 8; r++) { repOff[tid * 8 + r] = tot; tot += cnt[tid * 8 + r]; }
        runS[tid] = tot ? atomicAdd(&gcur1[tid], tot) : 0;
    }
    __syncthreads();
#pragma unroll
    for (int j = 0; j < EPT; j++)
        if (sup[j] >= 0)
            binned1[runS[sup[j]] + repOff[sup[j] * 8 + rep] + rnk[j]] = (unsigned)pk[j];
}

__global__ void k_bin2(const unsigned* __restrict__ binned1, const int* __restrict__ fillEnd,
                       int S, int capS, int* __restrict__ gcur2, unsigned* __restrict__ binned2) {
    __shared__ int send[SMAX];
    __shared__ int cnt[64 * 4];
    __shared__ int repOff[64 * 4];
    __shared__ int runS[64];
    int tid = threadIdx.x, rep = tid & 3;
    if (tid < S) send[tid] = fillEnd[tid];
    for (int i = tid; i < 64 * 4; i += 256) cnt[i] = 0;
    __syncthreads();
    int i0 = blockIdx.x * CE;
    int s0 = i0 / capS;
    int Sc = S * capS;
    unsigned pk[EPT];
    int rnk[EPT], rb[EPT];
#pragma unroll
    for (int j = 0; j < EPT; j++) {
        int idx = i0 + j * 256 + tid;
        rb[j] = -1;
        if (idx < Sc) {
            int sp = idx / capS;
            if (idx < send[sp]) {
                unsigned p = __builtin_nontemporal_load(binned1 + idx);
                int relB = ((sp - s0) << 5) | ((p >> RBITS) & (BPS - 1));
                pk[j] = p; rb[j] = relB;
                rnk[j] = atomicAdd(&cnt[relB * 4 + rep], 1);
            }
        }
    }
    __syncthreads();
    if (tid < 64) {
        int tot = 0;
#pragma unroll
        for (int r = 0; r < 4; r++) { repOff[tid * 4 + r] = tot; tot += cnt[tid * 4 + r]; }
        int sp = s0 + (tid >> 5);
        if (tot && sp < S) {
            int gb = sp * BPS + (tid & (BPS - 1));
            runS[tid] = atomicAdd(&gcur2[gb], tot);
        }
    }
    __syncthreads();
#pragma unroll
    for (int j = 0; j < EPT; j++)
        if (rb[j] >= 0) {
            unsigned p = pk[j];
            binned2[runS[rb[j]] + repOff[rb[j] * 4 + rep] + rnk[j]] =
                ((p >> SBITS) << RBITS) | (p & (RNODES - 1));
        }
}

// per-bucket counting sort -> padded ssort, row2[n]={beg,end}, dinv
__global__ void k_sortb2(const unsigned* __restrict__ binned2, const int* __restrict__ gcur2,
                         int capB, int N, int* __restrict__ ssort,
                         int2* __restrict__ row2, float* __restrict__ dinv) {
    __shared__ int cnt[RNODES];
    __shared__ int loc[RNODES];
    int b = blockIdx.x, tid = threadIdx.x;
    int beg = b * capB, end = gcur2[b];
    if (tid < RNODES) cnt[tid] = 0;
    __syncthreads();
    for (int idx = beg + tid; idx < end; idx += 256)
        atomicAdd(&cnt[__builtin_nontemporal_load(binned2 + idx) & (RNODES - 1)], 1);
    __syncthreads();
    if (tid < RNODES) loc[tid] = cnt[tid];
    __syncthreads();
    for (int off = 1; off < RNODES; off <<= 1) {
        int v = 0;
        if (tid < RNODES && tid >= off) v = loc[tid - off];
        __syncthreads();
        if (tid < RNODES) loc[tid] += v;
        __syncthreads();
    }
    int n0 = b << RBITS;
    if (tid < RNODES) {
        int excl = loc[tid] - cnt[tid];
        loc[tid] = beg + excl;
        int n = n0 + tid;
        if (n < N) {
            row2[n] = make_int2(beg + excl, beg + excl + cnt[tid]);
            dinv[n] = rsqrtf((float)cnt[tid] + 1.0f);   // +1 self loop
        }
    }
    if (tid < RNODES) cnt[tid] = 0;               // reuse as cursor
    __syncthreads();
    for (int idx = beg + tid; idx < end; idx += 256) {
        unsigned p = __builtin_nontemporal_load(binned2 + idx);
        int dl = (int)(p & (RNODES - 1));
        int r  = atomicAdd(&cnt[dl], 1);
        ssort[loc[dl] + r] = (int)(p >> RBITS);
    }
}

// ---------- layer 1 (+W12 fused) ----------
__global__ void k_prep1(const float* __restrict__ x, const float* __restrict__ dinv,
                        float4* __restrict__ p4, int N) {
    int n = blockIdx.x * blockDim.x + threadIdx.x;
    if (n >= N) return;
    float di = dinv[n];
    p4[n] = make_float4(x[n * 3] * di, x[n * 3 + 1] * di, x[n * 3 + 2] * di, 0.f);
}

// 32 lanes/node: lane-strided gather of p4[src], xor reduce-all, h1 per lane,
// then h1 @ W12 via LDS-staged h1 (broadcast reads, no permutes). No h in memory.
__global__ void k_l1g(const int2* __restrict__ row2, const int* __restrict__ ssort,
                      const float4* __restrict__ p4, const float* __restrict__ dinv,
                      const float* __restrict__ W1, const float* __restrict__ b1,
                      const float* __restrict__ W2, __half* __restrict__ g2, int N) {
    __shared__ float sW1[96];
    __shared__ float sb1[32];
    __shared__ float sW2[1024];
    __shared__ float sh1[256];
    int tid = threadIdx.x;
    for (int i = tid; i < 1024; i += 256) sW2[i] = W2[i];
    if (tid < 96) sW1[tid] = W1[tid];
    if (tid < 32) sb1[tid] = b1[tid];
    __syncthreads();
    int t = blockIdx.x * 256 + tid;
    int n = t >> 5, c = t & 31;
    bool active = (n < N);
    float ax = 0.f, ay = 0.f, az = 0.f;
    float di = 0.f;
    if (active) {
        int2 r = row2[n];
        for (int idx = r.x + c; idx < r.y; idx += 32) {
            float4 q = p4[__builtin_nontemporal_load(ssort + idx)];
            ax += q.x; ay += q.y; az += q.z;
        }
    }
#pragma unroll
    for (int off = 16; off; off >>= 1) {
        ax += __shfl_xor(ax, off, 32);
        ay += __shfl_xor(ay, off, 32);
        az += __shfl_xor(az, off, 32);
    }
    float h1 = 0.f;
    if (active) {
        float4 me = p4[n];
        di = dinv[n];
        ax = di * (ax + me.x); ay = di * (ay + me.y); az = di * (az + me.z);
        h1 = fmaxf(ax * sW1[c] + ay * sW1[32 + c] + az * sW1[64 + c] + sb1[c], 0.f);
    }
    sh1[tid] = h1;
    __syncthreads();
    if (!active) return;
    const float* hr = sh1 + (tid >> 5) * 32;
    float acc = 0.f;
#pragma unroll
    for (int k = 0; k < 32; k++) acc += hr[k] * sW2[k * 32 + c];
    g2[(size_t)n * 32 + c] = __float2half_rn(acc * di);
}

// ---------- layer 2 aggregate: 16 lanes/node, lane = 2 channels, 8-deep MLP ----
__global__ void k_agg16(const int2* __restrict__ row2, const int* __restrict__ ssort,
                        const __half2* __restrict__ g2, const float* __restrict__ dinv,
                        const float* __restrict__ bias, float* __restrict__ h, int N) {
    int t = blockIdx.x * blockDim.x + threadIdx.x;
    int n = t >> 4, l = t & 15;
    if (n >= N) return;
    int2 r = row2[n];
    int beg = r.x, end = r.y;
    float ax = 0.f, ay = 0.f, bx = 0.f, by = 0.f;
    float cx = 0.f, cy = 0.f, dx = 0.f, dy = 0.f;
    float ex = 0.f, ey = 0.f, fx = 0.f, fy = 0.f;
    float gx = 0.f, gy = 0.f, hx = 0.f, hy = 0.f;
    int base = beg;
    int m = end - base; if (m > 16) m = 16;
    int myS = (m > 0 && l < m) ? __builtin_nontemporal_load(ssort + base + l) : 0;
    while (base < end) {
        // prefetch next chunk's indices before consuming current chunk
        int nbase = base + 16;
        int nm = end - nbase; if (nm > 16) nm = 16;
        int nS = (nm > 0 && l < nm) ? __builtin_nontemporal_load(ssort + nbase + l) : 0;
        int i = 0;
        for (; i + 8 <= m; i += 8) {
            int s0 = __shfl(myS, i,     16);
            int s1 = __shfl(myS, i + 1, 16);
            int s2 = __shfl(myS, i + 2, 16);
            int s3 = __shfl(myS, i + 3, 16);
            int s4 = __shfl(myS, i + 4, 16);
            int s5 = __shfl(myS, i + 5, 16);
            int s6 = __shfl(myS, i + 6, 16);
            int s7 = __shfl(myS, i + 7, 16);
            float2 q0 = __half22float2(g2[(size_t)s0 * 16 + l]);
            float2 q1 = __half22float2(g2[(size_t)s1 * 16 + l]);
            float2 q2 = __half22float2(g2[(size_t)s2 * 16 + l]);
            float2 q3 = __half22float2(g2[(size_t)s3 * 16 + l]);
            float2 q4 = __half22float2(g2[(size_t)s4 * 16 + l]);
            float2 q5 = __half22float2(g2[(size_t)s5 * 16 + l]);
            float2 q6 = __half22float2(g2[(size_t)s6 * 16 + l]);
            float2 q7 = __half22float2(g2[(size_t)s7 * 16 + l]);
            ax += q0.x; ay += q0.y;
            bx += q1.x; by += q1.y;
            cx += q2.x; cy += q2.y;
            dx += q3.x; dy += q3.y;
            ex += q4.x; ey += q4.y;
            fx += q5.x; fy += q5.y;
            gx += q6.x; gy += q6.y;
            hx += q7.x; hy += q7.y;
        }
        for (; i + 4 <= m; i += 4) {
            int s0 = __shfl(myS, i,     16);
            int s1 = __shfl(myS, i + 1, 16);
            int s2 = __shfl(myS, i + 2, 16);
            int s3 = __shfl(myS, i + 3, 16);
            float2 q0 = __half22float2(g2[(size_t)s0 * 16 + l]);
            float2 q1 = __half22float2(g2[(size_t)s1 * 16 + l]);
            float2 q2 = __half22float2(g2[(size_t)s2 * 16 + l]);
            float2 q3 = __half22float2(g2[(size_t)s3 * 16 + l]);
            ax += q0.x; ay += q0.y;
            bx += q1.x; by += q1.y;
            cx += q2.x; cy += q2.y;
            dx += q3.x; dy += q3.y;
        }
        for (; i < m; i++) {
            int s = __shfl(myS, i, 16);
            float2 q = __half22float2(g2[(size_t)s * 16 + l]);
            ax += q.x; ay += q.y;
        }
        base = nbase; m = nm; myS = nS;
    }
    float2 self = __half22float2(g2[(size_t)n * 16 + l]);
    float sx = (((ax + bx) + (cx + dx)) + ((ex + fx) + (gx + hx))) + self.x;
    float sy = (((ay + by) + (cy + dy)) + ((ey + fy) + (gy + hy))) + self.y;
    float di = dinv[n];
    int c0 = l * 2;
    float2 o = make_float2(fmaxf(di * sx + bias[c0], 0.f),
                           fmaxf(di * sy + bias[c0 + 1], 0.f));
    double od; __builtin_memcpy(&od, &o, 8);
    __builtin_nontemporal_store(od, (double*)(h + (size_t)n * 32 + c0));
}

// ---------- gemv h -> fp16 g ----------
__global__ void k_gemv32h(const float* __restrict__ h, const float* __restrict__ W,
                          const float* __restrict__ dinv, __half* __restrict__ g, int N) {
    __shared__ float sW[1024];
    __shared__ float sh[256];
    int tid = threadIdx.x;
    for (int i = tid; i < 1024; i += 256) sW[i] = W[i];
    int t = blockIdx.x * 256 + tid;
    if (t < N * 32) sh[tid] = h[t];
    __syncthreads();
    int n = t >> 5, c = t & 31;
    if (n >= N) return;
    const float* hr = sh + (tid >> 5) * 32;
    float acc = 0.f;
#pragma unroll
    for (int k = 0; k < 32; k++) acc += hr[k] * sW[k * 32 + c];
    g[t] = __float2half_rn(acc * dinv[n]);
}

// ---------- layer 3 aggregate + FC head: same 8-deep MLP structure ----------
__global__ void k_agg16_fc(const int2* __restrict__ row2, const int* __restrict__ ssort,
                           const __half2* __restrict__ g2, const float* __restrict__ dinv,
                           const float* __restrict__ bias, const float* __restrict__ fcw,
                           const float* __restrict__ fcb, float* __restrict__ out, int N) {
    int t = blockIdx.x * blockDim.x + threadIdx.x;
    int n = t >> 4, l = t & 15;
    if (n >= N) return;
    int2 r = row2[n];
    int beg = r.x, end = r.y;
    float ax = 0.f, ay = 0.f, bx = 0.f, by = 0.f;
    float cx = 0.f, cy = 0.f, dx = 0.f, dy = 0.f;
    float ex = 0.f, ey = 0.f, fx = 0.f, fy = 0.f;
    float gx = 0.f, gy = 0.f, hx = 0.f, hy = 0.f;
    int base = beg;
    int m = end - base; if (m > 16) m = 16;
    int myS = (m > 0 && l < m) ? __builtin_nontemporal_load(ssort + base + l) : 0;
    while (base < end) {
        int nbase = base + 16;
        int nm = end - nbase; if (nm > 16) nm = 16;
        int nS = (nm > 0 && l < nm) ? __builtin_nontemporal_load(ssort + nbase + l) : 0;
        int i = 0;
        for (; i + 8 <= m; i += 8) {
            int s0 = __shfl(myS, i,     16);
            int s1 = __shfl(myS, i + 1, 16);
            int s2 = __shfl(myS, i + 2, 16);
            int s3 = __shfl(myS, i + 3, 16);
            int s4 = __shfl(myS, i + 4, 16);
            int s5 = __shfl(myS, i + 5, 16);
            int s6 = __shfl(myS, i + 6, 16);
            int s7 = __shfl(myS, i + 7, 16);
            float2 q0 = __half22float2(g2[(size_t)s0 * 16 + l]);
            float2 q1 = __half22float2(g2[(size_t)s1 * 16 + l]);
            float2 q2 = __half22float2(g2[(size_t)s2 * 16 + l]);
            float2 q3 = __half22float2(g2[(size_t)s3 * 16 + l]);
            float2 q4 = __half22float2(g2[(size_t)s4 * 16 + l]);
            float2 q5 = __half22float2(g2[(size_t)s5 * 16 + l]);
            float2 q6 = __half22float2(g2[(size_t)s6 * 16 + l]);
            float2 q7 = __half22float2(g2[(size_t)s7 * 16 + l]);
            ax += q0.x; ay += q0.y;
            bx += q1.x; by += q1.y;
            cx += q2.x; cy += q2.y;
            dx += q3.x; dy += q3.y;
            ex += q4.x; ey += q4.y;
            fx += q5.x; fy += q5.y;
            gx += q6.x; gy += q6.y;
            hx += q7.x; hy += q7.y;
        }
        for (; i + 4 <= m; i += 4) {
            int s0 = __shfl(myS, i,     16);
            int s1 = __shfl(myS, i + 1, 16);
            int s2 = __shfl(myS, i + 2, 16);
            int s3 = __shfl(myS, i + 3, 16);
            float2 q0 = __half22float2(g2[(size_t)s0 * 16 + l]);
            float2 q1 = __half22float2(g2[(size_t)s1 * 16 + l]);
            float2 q2 = __half22float2(g2[(size_t)s2 * 16 + l]);
            float2 q3 = __half22float2(g2[(size_t)s3 * 16 + l]);
            ax += q0.x; ay += q0.y;
            bx += q1.x; by += q1.y;
            cx += q2.x; cy += q2.y;
            dx += q3.x; dy += q3.y;
        }
        for (; i < m; i++) {
            int s = __shfl(myS, i, 16);
            float2 q = __half22float2(g2[(size_t)s * 16 + l]);
            ax += q.x; ay += q.y;
        }
        base = nbase; m = nm; myS = nS;
    }
    float2 self = __half22float2(g2[(size_t)n * 16 + l]);
    float sx = (((ax + bx) + (cx + dx)) + ((ex + fx) + (gx + hx))) + self.x;
    float sy = (((ay + by) + (cy + dy)) + ((ey + fy) + (gy + hy))) + self.y;
    float di = dinv[n];
    int c0 = l * 2;
    float v = fmaxf(di * sx + bias[c0], 0.f) * fcw[c0]
            + fmaxf(di * sy + bias[c0 + 1], 0.f) * fcw[c0 + 1];
    v += __shfl_down(v, 8, 16);
    v += __shfl_down(v, 4, 16);
    v += __shfl_down(v, 2, 16);
    v += __shfl_down(v, 1, 16);
    if (l == 0) out[n] = v + fcb[0];
}

extern "C" void kernel_launch(void* const* d_in, const int* in_sizes, int n_in,
                              void* d_out, int out_size, void* d_ws, size_t ws_size,
                              hipStream_t stream) {
    const float* x1  = (const float*)d_in[0];
    const int*   ei  = (const int*)d_in[1];
    const float* W11 = (const float*)d_in[2];
    const float* b11 = (const float*)d_in[3];
    const float* W12 = (const float*)d_in[4];
    const float* b12 = (const float*)d_in[5];
    const float* W13 = (const float*)d_in[6];
    const float* b13 = (const float*)d_in[7];
    const float* fcw = (const float*)d_in[8];
    const float* fcb = (const float*)d_in[9];
    float* out = (float*)d_out;

    const int N = in_sizes[0] / 3;
    const int E = in_sizes[1] / 2;
    const int* src = ei;
    const int* dst = ei + E;

    const int B = (N + RNODES - 1) / RNODES;      // 782 buckets
    const int S = (N + SNODES - 1) / SNODES;      // 25 supers
    const int capS = E / S + E / S / 16 + 1024;   // ~7% + 1K slack
    const int capB = E / B + E / B / 4 + 256;     // ~31% slack
    const size_t NC = (size_t)N * 32;

    // workspace layout (4-byte words); keep 8B alignment for h/row2/p4.
    float4*   p4      = (float4*)d_ws;                       // 4N words
    __half*   g       = (__half*)(p4 + N);                   // NC halfs = NC/2 words
    int2*     row2    = (int2*)(g + NC);                     // 2N words
    float*    dinv    = (float*)(row2 + N);                  // N
    int*      gcur1   = (int*)(dinv + N);                    // 32 (padded)
    int*      gcur2   = gcur1 + 32;                          // 800 (padded)
    unsigned* binned1 = (unsigned*)(gcur2 + 800);            // S*capS
    unsigned* binned2 = binned1 + (size_t)S * capS;          // B*capB
    int*      ssort   = (int*)(binned2 + (size_t)B * capB);  // B*capB
    float*    h       = (float*)binned1;                     // NC floats (binned1 dead)

    dim3 blk(256);
    dim3 grid_nc(((int)NC + 255) / 256);
    dim3 grid_n((N + 255) / 256);
    dim3 grid_n16(((N * 16) + 255) / 256);
    dim3 grid_e((E + CE - 1) / CE);
    dim3 grid_sc((S * capS + CE - 1) / CE);
    dim3 grid_b(B);

    // ---- preprocessing (no memsets, no prescan) ----
    k_init<<<dim3((B + 255) / 256), blk, 0, stream>>>(S, B, capS, capB, gcur1, gcur2);
    k_bin1<<<grid_e, blk, 0, stream>>>(src, dst, E, S, gcur1, binned1);
    k_bin2<<<grid_sc, blk, 0, stream>>>(binned1, gcur1, S, capS, gcur2, binned2);
    k_sortb2<<<grid_b, blk, 0, stream>>>(binned2, gcur2, capB, N, ssort, row2, dinv);

    // ---- layer 1 (+ W12 fused) ----
    k_prep1<<<grid_n, blk, 0, stream>>>(x1, dinv, p4, N);
    k_l1g<<<grid_nc, blk, 0, stream>>>(row2, ssort, p4, dinv, W11, b11, W12, g, N);

    // ---- layer 2 ----
    k_agg16<<<grid_n16, blk, 0, stream>>>(row2, ssort, (const __half2*)g, dinv, b12, h, N);
    k_gemv32h<<<grid_nc, blk, 0, stream>>>(h, W13, dinv, g, N);

    // ---- layer 3 + FC head ----
    k_agg16_fc<<<grid_n16, blk, 0, stream>>>(row2, ssort, (const __half2*)g, dinv, b13, fcw, fcb, out, N);
}

// Round 3
// 211.728 us; speedup vs baseline: 1.3964x; 1.0665x over previous
//
#include <hip/hip_runtime.h>
#include <hip/hip_bf16.h>
#include <hip/hip_fp16.h>

// 3-layer GCN + FC head. No-prescan padded two-pass radix preprocessing:
//   k_init  : cursors = fixed region starts (super s: s*capS; bucket b: b*capB)
//   k_bin1  : bin edges by dst-super (25 regions), LDS rank, clustered writes
//   k_bin2  : bin by dst-bucket within super (782 padded regions)
//   k_sortb2: per-bucket counting sort -> padded ssort + row2[n]={beg,end} + dinv
//             + fused p4 = dinv*x (prep1 folded in)
// Layers:
//   k_l1g   : agg3 -> relu(.@W11+b11) -> @W12*dinv -> g (fp16)  [32 lanes/node]
//   k_agg16g: gather g -> h=relu(dinv*acc+b12) -> (h@W13)*dinv -> gout (fp16)
//             [16 lanes/node, 8-deep MLP, ssort prefetch, LDS gemv fusion]
//   k_agg16_fc: gather gout -> relu(dinv*acc+b13).fcw + fcb -> out

#define RBITS  7
#define RNODES 128
#define SBITS  12
#define SNODES 4096
#define BPS    32
#define SMAX   32
#define CE     4096
#define EPT    16

// ---------- preprocessing ----------
__global__ void k_init(int S, int B, int capS, int capB,
                       int* __restrict__ gcur1, int* __restrict__ gcur2) {
    int t = blockIdx.x * blockDim.x + threadIdx.x;
    if (t < S) gcur1[t] = t * capS;
    if (t < B) gcur2[t] = t * capB;
}

__global__ void k_bin1(const int* __restrict__ src, const int* __restrict__ dst, int E, int S,
                       int* __restrict__ gcur1, unsigned* __restrict__ binned1) {
    __shared__ int cnt[SMAX * 8];
    __shared__ int repOff[SMAX * 8];
    __shared__ int runS[SMAX];
    int tid = threadIdx.x, rep = tid & 7;
    for (int i = tid; i < SMAX * 8; i += 256) cnt[i] = 0;
    __syncthreads();
    int e0 = blockIdx.x * CE;
    int pk[EPT], rnk[EPT], sup[EPT];
#pragma unroll
    for (int j = 0; j < EPT; j++) {
        int e = e0 + j * 256 + tid;
        if (e < E) {
            int d = __builtin_nontemporal_load(dst + e);
            sup[j] = d >> SBITS;
            pk[j]  = (__builtin_nontemporal_load(src + e) << SBITS) | (d & (SNODES - 1));
            rnk[j] = atomicAdd(&cnt[sup[j] * 8 + rep], 1);
        } else sup[j] = -1;
    }
    __syncthreads();
    if (tid < S) {
        int tot = 0;
#pragma unroll
        for (int r = 0; r < 8; r++) { repOff[tid * 8 + r] = tot; tot += cnt[tid * 8 + r]; }
        runS[tid] = tot ? atomicAdd(&gcur1[tid], tot) : 0;
    }
    __syncthreads();
#pragma unroll
    for (int j = 0; j < EPT; j++)
        if (sup[j] >= 0)
            binned1[runS[sup[j]] + repOff[sup[j] * 8 + rep] + rnk[j]] = (unsigned)pk[j];
}

__global__ void k_bin2(const unsigned* __restrict__ binned1, const int* __restrict__ fillEnd,
                       int S, int capS, int* __restrict__ gcur2, unsigned* __restrict__ binned2) {
    __shared__ int send[SMAX];
    __shared__ int cnt[64 * 4];
    __shared__ int repOff[64 * 4];
    __shared__ int runS[64];
    int tid = threadIdx.x, rep = tid & 3;
    if (tid < S) send[tid] = fillEnd[tid];
    for (int i = tid; i < 64 * 4; i += 256) cnt[i] = 0;
    __syncthreads();
    int i0 = blockIdx.x * CE;
    int s0 = i0 / capS;
    int Sc = S * capS;
    unsigned pk[EPT];
    int rnk[EPT], rb[EPT];
#pragma unroll
    for (int j = 0; j < EPT; j++) {
        int idx = i0 + j * 256 + tid;
        rb[j] = -1;
        if (idx < Sc) {
            int sp = idx / capS;
            if (idx < send[sp]) {
                unsigned p = __builtin_nontemporal_load(binned1 + idx);
                int relB = ((sp - s0) << 5) | ((p >> RBITS) & (BPS - 1));
                pk[j] = p; rb[j] = relB;
                rnk[j] = atomicAdd(&cnt[relB * 4 + rep], 1);
            }
        }
    }
    __syncthreads();
    if (tid < 64) {
        int tot = 0;
#pragma unroll
        for (int r = 0; r < 4; r++) { repOff[tid * 4 + r] = tot; tot += cnt[tid * 4 + r]; }
        int sp = s0 + (tid >> 5);
        if (tot && sp < S) {
            int gb = sp * BPS + (tid & (BPS - 1));
            runS[tid] = atomicAdd(&gcur2[gb], tot);
        }
    }
    __syncthreads();
#pragma unroll
    for (int j = 0; j < EPT; j++)
        if (rb[j] >= 0) {
            unsigned p = pk[j];
            binned2[runS[rb[j]] + repOff[rb[j] * 4 + rep] + rnk[j]] =
                ((p >> SBITS) << RBITS) | (p & (RNODES - 1));
        }
}

// per-bucket counting sort -> padded ssort, row2[n]={beg,end}, dinv, p4=dinv*x
__global__ void k_sortb2(const unsigned* __restrict__ binned2, const int* __restrict__ gcur2,
                         int capB, int N, int* __restrict__ ssort,
                         int2* __restrict__ row2, float* __restrict__ dinv,
                         const float* __restrict__ x, float4* __restrict__ p4) {
    __shared__ int cnt[RNODES];
    __shared__ int loc[RNODES];
    int b = blockIdx.x, tid = threadIdx.x;
    int beg = b * capB, end = gcur2[b];
    if (tid < RNODES) cnt[tid] = 0;
    __syncthreads();
    for (int idx = beg + tid; idx < end; idx += 256)
        atomicAdd(&cnt[__builtin_nontemporal_load(binned2 + idx) & (RNODES - 1)], 1);
    __syncthreads();
    if (tid < RNODES) loc[tid] = cnt[tid];
    __syncthreads();
    for (int off = 1; off < RNODES; off <<= 1) {
        int v = 0;
        if (tid < RNODES && tid >= off) v = loc[tid - off];
        __syncthreads();
        if (tid < RNODES) loc[tid] += v;
        __syncthreads();
    }
    int n0 = b << RBITS;
    if (tid < RNODES) {
        int excl = loc[tid] - cnt[tid];
        loc[tid] = beg + excl;
        int n = n0 + tid;
        if (n < N) {
            row2[n] = make_int2(beg + excl, beg + excl + cnt[tid]);
            float dv = rsqrtf((float)cnt[tid] + 1.0f);   // +1 self loop
            dinv[n] = dv;
            p4[n] = make_float4(x[n * 3] * dv, x[n * 3 + 1] * dv,
                                x[n * 3 + 2] * dv, 0.f);
        }
    }
    if (tid < RNODES) cnt[tid] = 0;               // reuse as cursor
    __syncthreads();
    for (int idx = beg + tid; idx < end; idx += 256) {
        unsigned p = __builtin_nontemporal_load(binned2 + idx);
        int dl = (int)(p & (RNODES - 1));
        int r  = atomicAdd(&cnt[dl], 1);
        ssort[loc[dl] + r] = (int)(p >> RBITS);
    }
}

// ---------- layer 1 (+W12 fused) ----------
// 32 lanes/node: lane-strided gather of p4[src], xor reduce-all, h1 per lane,
// then h1 @ W12 via LDS-staged h1 (broadcast reads, no permutes). No h in memory.
__global__ void k_l1g(const int2* __restrict__ row2, const int* __restrict__ ssort,
                      const float4* __restrict__ p4, const float* __restrict__ dinv,
                      const float* __restrict__ W1, const float* __restrict__ b1,
                      const float* __restrict__ W2, __half* __restrict__ g2, int N) {
    __shared__ float sW1[96];
    __shared__ float sb1[32];
    __shared__ float sW2[1024];
    __shared__ float sh1[256];
    int tid = threadIdx.x;
    for (int i = tid; i < 1024; i += 256) sW2[i] = W2[i];
    if (tid < 96) sW1[tid] = W1[tid];
    if (tid < 32) sb1[tid] = b1[tid];
    __syncthreads();
    int t = blockIdx.x * 256 + tid;
    int n = t >> 5, c = t & 31;
    bool active = (n < N);
    float ax = 0.f, ay = 0.f, az = 0.f;
    float di = 0.f;
    if (active) {
        int2 r = row2[n];
        for (int idx = r.x + c; idx < r.y; idx += 32) {
            float4 q = p4[__builtin_nontemporal_load(ssort + idx)];
            ax += q.x; ay += q.y; az += q.z;
        }
    }
#pragma unroll
    for (int off = 16; off; off >>= 1) {
        ax += __shfl_xor(ax, off, 32);
        ay += __shfl_xor(ay, off, 32);
        az += __shfl_xor(az, off, 32);
    }
    float h1 = 0.f;
    if (active) {
        float4 me = p4[n];
        di = dinv[n];
        ax = di * (ax + me.x); ay = di * (ay + me.y); az = di * (az + me.z);
        h1 = fmaxf(ax * sW1[c] + ay * sW1[32 + c] + az * sW1[64 + c] + sb1[c], 0.f);
    }
    sh1[tid] = h1;
    __syncthreads();
    if (!active) return;
    const float* hr = sh1 + (tid >> 5) * 32;
    float acc = 0.f;
#pragma unroll
    for (int k = 0; k < 32; k++) acc += hr[k] * sW2[k * 32 + c];
    g2[(size_t)n * 32 + c] = __float2half_rn(acc * di);
}

// ---------- layer 2 aggregate + W13 gemv fused ----------
// 16 lanes/node, lane = 2 channels, 8-deep MLP gather; then h-row staged in
// LDS (pad 33 to avoid 4-way bank conflict), gemv (h@W13)*dinv -> gout fp16.
__global__ void k_agg16g(const int2* __restrict__ row2, const int* __restrict__ ssort,
                         const __half2* __restrict__ g2, const float* __restrict__ dinv,
                         const float* __restrict__ bias, const float* __restrict__ W3,
                         __half* __restrict__ gout, int N) {
    __shared__ float sW[1024];
    __shared__ float sh[16 * 33];
    int tid = threadIdx.x;
    for (int i = tid; i < 1024; i += 256) sW[i] = W3[i];
    int t = blockIdx.x * 256 + tid;
    int n = t >> 4, l = t & 15;
    int c0 = l * 2;
    bool act = (n < N);
    float di = 0.f;
    if (act) {
        int2 r = row2[n];
        int beg = r.x, end = r.y;
        float ax = 0.f, ay = 0.f, bx = 0.f, by = 0.f;
        float cx = 0.f, cy = 0.f, dx = 0.f, dy = 0.f;
        float ex = 0.f, ey = 0.f, fx = 0.f, fy = 0.f;
        float gx = 0.f, gy = 0.f, hx = 0.f, hy = 0.f;
        int base = beg;
        int m = end - base; if (m > 16) m = 16;
        int myS = (m > 0 && l < m) ? __builtin_nontemporal_load(ssort + base + l) : 0;
        while (base < end) {
            int nbase = base + 16;
            int nm = end - nbase; if (nm > 16) nm = 16;
            int nS = (nm > 0 && l < nm) ? __builtin_nontemporal_load(ssort + nbase + l) : 0;
            int i = 0;
            for (; i + 8 <= m; i += 8) {
                int s0 = __shfl(myS, i,     16);
                int s1 = __shfl(myS, i + 1, 16);
                int s2 = __shfl(myS, i + 2, 16);
                int s3 = __shfl(myS, i + 3, 16);
                int s4 = __shfl(myS, i + 4, 16);
                int s5 = __shfl(myS, i + 5, 16);
                int s6 = __shfl(myS, i + 6, 16);
                int s7 = __shfl(myS, i + 7, 16);
                float2 q0 = __half22float2(g2[(size_t)s0 * 16 + l]);
                float2 q1 = __half22float2(g2[(size_t)s1 * 16 + l]);
                float2 q2 = __half22float2(g2[(size_t)s2 * 16 + l]);
                float2 q3 = __half22float2(g2[(size_t)s3 * 16 + l]);
                float2 q4 = __half22float2(g2[(size_t)s4 * 16 + l]);
                float2 q5 = __half22float2(g2[(size_t)s5 * 16 + l]);
                float2 q6 = __half22float2(g2[(size_t)s6 * 16 + l]);
                float2 q7 = __half22float2(g2[(size_t)s7 * 16 + l]);
                ax += q0.x; ay += q0.y;
                bx += q1.x; by += q1.y;
                cx += q2.x; cy += q2.y;
                dx += q3.x; dy += q3.y;
                ex += q4.x; ey += q4.y;
                fx += q5.x; fy += q5.y;
                gx += q6.x; gy += q6.y;
                hx += q7.x; hy += q7.y;
            }
            for (; i + 4 <= m; i += 4) {
                int s0 = __shfl(myS, i,     16);
                int s1 = __shfl(myS, i + 1, 16);
                int s2 = __shfl(myS, i + 2, 16);
                int s3 = __shfl(myS, i + 3, 16);
                float2 q0 = __half22float2(g2[(size_t)s0 * 16 + l]);
                float2 q1 = __half22float2(g2[(size_t)s1 * 16 + l]);
                float2 q2 = __half22float2(g2[(size_t)s2 * 16 + l]);
                float2 q3 = __half22float2(g2[(size_t)s3 * 16 + l]);
                ax += q0.x; ay += q0.y;
                bx += q1.x; by += q1.y;
                cx += q2.x; cy += q2.y;
                dx += q3.x; dy += q3.y;
            }
            for (; i < m; i++) {
                int s = __shfl(myS, i, 16);
                float2 q = __half22float2(g2[(size_t)s * 16 + l]);
                ax += q.x; ay += q.y;
            }
            base = nbase; m = nm; myS = nS;
        }
        float2 self = __half22float2(g2[(size_t)n * 16 + l]);
        float sx = (((ax + bx) + (cx + dx)) + ((ex + fx) + (gx + hx))) + self.x;
        float sy = (((ay + by) + (cy + dy)) + ((ey + fy) + (gy + hy))) + self.y;
        di = dinv[n];
        int nn = tid >> 4;
        sh[nn * 33 + c0]     = fmaxf(di * sx + bias[c0], 0.f);
        sh[nn * 33 + c0 + 1] = fmaxf(di * sy + bias[c0 + 1], 0.f);
    }
    __syncthreads();
    if (!act) return;
    const float* hr = sh + (tid >> 4) * 33;
    float a0 = 0.f, a1 = 0.f;
#pragma unroll
    for (int k = 0; k < 32; k++) {
        float hv = hr[k];
        float2 w = *(const float2*)(sW + k * 32 + c0);
        a0 += hv * w.x; a1 += hv * w.y;
    }
    __half2 o = __floats2half2_rn(a0 * di, a1 * di);
    *(__half2*)(gout + (size_t)n * 32 + c0) = o;
}

// ---------- layer 3 aggregate + FC head: 8-deep MLP structure ----------
__global__ void k_agg16_fc(const int2* __restrict__ row2, const int* __restrict__ ssort,
                           const __half2* __restrict__ g2, const float* __restrict__ dinv,
                           const float* __restrict__ bias, const float* __restrict__ fcw,
                           const float* __restrict__ fcb, float* __restrict__ out, int N) {
    int t = blockIdx.x * blockDim.x + threadIdx.x;
    int n = t >> 4, l = t & 15;
    if (n >= N) return;
    int2 r = row2[n];
    int beg = r.x, end = r.y;
    float ax = 0.f, ay = 0.f, bx = 0.f, by = 0.f;
    float cx = 0.f, cy = 0.f, dx = 0.f, dy = 0.f;
    float ex = 0.f, ey = 0.f, fx = 0.f, fy = 0.f;
    float gx = 0.f, gy = 0.f, hx = 0.f, hy = 0.f;
    int base = beg;
    int m = end - base; if (m > 16) m = 16;
    int myS = (m > 0 && l < m) ? __builtin_nontemporal_load(ssort + base + l) : 0;
    while (base < end) {
        int nbase = base + 16;
        int nm = end - nbase; if (nm > 16) nm = 16;
        int nS = (nm > 0 && l < nm) ? __builtin_nontemporal_load(ssort + nbase + l) : 0;
        int i = 0;
        for (; i + 8 <= m; i += 8) {
            int s0 = __shfl(myS, i,     16);
            int s1 = __shfl(myS, i + 1, 16);
            int s2 = __shfl(myS, i + 2, 16);
            int s3 = __shfl(myS, i + 3, 16);
            int s4 = __shfl(myS, i + 4, 16);
            int s5 = __shfl(myS, i + 5, 16);
            int s6 = __shfl(myS, i + 6, 16);
            int s7 = __shfl(myS, i + 7, 16);
            float2 q0 = __half22float2(g2[(size_t)s0 * 16 + l]);
            float2 q1 = __half22float2(g2[(size_t)s1 * 16 + l]);
            float2 q2 = __half22float2(g2[(size_t)s2 * 16 + l]);
            float2 q3 = __half22float2(g2[(size_t)s3 * 16 + l]);
            float2 q4 = __half22float2(g2[(size_t)s4 * 16 + l]);
            float2 q5 = __half22float2(g2[(size_t)s5 * 16 + l]);
            float2 q6 = __half22float2(g2[(size_t)s6 * 16 + l]);
            float2 q7 = __half22float2(g2[(size_t)s7 * 16 + l]);
            ax += q0.x; ay += q0.y;
            bx += q1.x; by += q1.y;
            cx += q2.x; cy += q2.y;
            dx += q3.x; dy += q3.y;
            ex += q4.x; ey += q4.y;
            fx += q5.x; fy += q5.y;
            gx += q6.x; gy += q6.y;
            hx += q7.x; hy += q7.y;
        }
        for (; i + 4 <= m; i += 4) {
            int s0 = __shfl(myS, i,     16);
            int s1 = __shfl(myS, i + 1, 16);
            int s2 = __shfl(myS, i + 2, 16);
            int s3 = __shfl(myS, i + 3, 16);
            float2 q0 = __half22float2(g2[(size_t)s0 * 16 + l]);
            float2 q1 = __half22float2(g2[(size_t)s1 * 16 + l]);
            float2 q2 = __half22float2(g2[(size_t)s2 * 16 + l]);
            float2 q3 = __half22float2(g2[(size_t)s3 * 16 + l]);
            ax += q0.x; ay += q0.y;
            bx += q1.x; by += q1.y;
            cx += q2.x; cy += q2.y;
            dx += q3.x; dy += q3.y;
        }
        for (; i < m; i++) {
            int s = __shfl(myS, i, 16);
            float2 q = __half22float2(g2[(size_t)s * 16 + l]);
            ax += q.x; ay += q.y;
        }
        base = nbase; m = nm; myS = nS;
    }
    float2 self = __half22float2(g2[(size_t)n * 16 + l]);
    float sx = (((ax + bx) + (cx + dx)) + ((ex + fx) + (gx + hx))) + self.x;
    float sy = (((ay + by) + (cy + dy)) + ((ey + fy) + (gy + hy))) + self.y;
    float di = dinv[n];
    int c0 = l * 2;
    float v = fmaxf(di * sx + bias[c0], 0.f) * fcw[c0]
            + fmaxf(di * sy + bias[c0 + 1], 0.f) * fcw[c0 + 1];
    v += __shfl_down(v, 8, 16);
    v += __shfl_down(v, 4, 16);
    v += __shfl_down(v, 2, 16);
    v += __shfl_down(v, 1, 16);
    if (l == 0) out[n] = v + fcb[0];
}

extern "C" void kernel_launch(void* const* d_in, const int* in_sizes, int n_in,
                              void* d_out, int out_size, void* d_ws, size_t ws_size,
                              hipStream_t stream) {
    const float* x1  = (const float*)d_in[0];
    const int*   ei  = (const int*)d_in[1];
    const float* W11 = (const float*)d_in[2];
    const float* b11 = (const float*)d_in[3];
    const float* W12 = (const float*)d_in[4];
    const float* b12 = (const float*)d_in[5];
    const float* W13 = (const float*)d_in[6];
    const float* b13 = (const float*)d_in[7];
    const float* fcw = (const float*)d_in[8];
    const float* fcb = (const float*)d_in[9];
    float* out = (float*)d_out;

    const int N = in_sizes[0] / 3;
    const int E = in_sizes[1] / 2;
    const int* src = ei;
    const int* dst = ei + E;

    const int B = (N + RNODES - 1) / RNODES;      // 782 buckets
    const int S = (N + SNODES - 1) / SNODES;      // 25 supers
    const int capS = E / S + E / S / 16 + 1024;   // ~7% + 1K slack
    const int capB = E / B + E / B / 4 + 256;     // ~31% slack
    const size_t NC = (size_t)N * 32;

    // workspace layout (4-byte words); keep 8B alignment for row2/p4.
    float4*   p4      = (float4*)d_ws;                       // 4N words
    __half*   g       = (__half*)(p4 + N);                   // NC halfs = NC/2 words
    int2*     row2    = (int2*)(g + NC);                     // 2N words
    float*    dinv    = (float*)(row2 + N);                  // N
    int*      gcur1   = (int*)(dinv + N);                    // 32 (padded)
    int*      gcur2   = gcur1 + 32;                          // 800 (padded)
    unsigned* binned1 = (unsigned*)(gcur2 + 800);            // S*capS
    unsigned* binned2 = binned1 + (size_t)S * capS;          // B*capB
    int*      ssort   = (int*)(binned2 + (size_t)B * capB);  // B*capB
    __half*   gout    = (__half*)binned1;                    // NC halfs (binned1 dead)

    dim3 blk(256);
    dim3 grid_nc(((int)NC + 255) / 256);
    dim3 grid_n16(((N * 16) + 255) / 256);
    dim3 grid_e((E + CE - 1) / CE);
    dim3 grid_sc((S * capS + CE - 1) / CE);
    dim3 grid_b(B);

    // ---- preprocessing (no memsets, no prescan) ----
    k_init<<<dim3((B + 255) / 256), blk, 0, stream>>>(S, B, capS, capB, gcur1, gcur2);
    k_bin1<<<grid_e, blk, 0, stream>>>(src, dst, E, S, gcur1, binned1);
    k_bin2<<<grid_sc, blk, 0, stream>>>(binned1, gcur1, S, capS, gcur2, binned2);
    k_sortb2<<<grid_b, blk, 0, stream>>>(binned2, gcur2, capB, N, ssort, row2, dinv, x1, p4);

    // ---- layer 1 (+ W12 fused) ----
    k_l1g<<<grid_nc, blk, 0, stream>>>(row2, ssort, p4, dinv, W11, b11, W12, g, N);

    // ---- layer 2 aggregate + W13 gemv fused ----
    k_agg16g<<<grid_n16, blk, 0, stream>>>(row2, ssort, (const __half2*)g, dinv, b12, W13, gout, N);

    // ---- layer 3 + FC head ----
    k_agg16_fc<<<grid_n16, blk, 0, stream>>>(row2, ssort, (const __half2*)gout, dinv, b13, fcw, fcb, out, N);
}